// Round 9
// baseline (122.146 us; speedup 1.0000x reference)
//
#include <hip/hip_runtime.h>

#define NN 2048
#define FF 128
#define SLOPE 0.1f
#define WSTR 136    // bf16 LDS stride for transposed 128x128 weights
#define TSTR 136    // bf16 LDS stride for 64-row tiles

typedef __attribute__((ext_vector_type(8))) short short8;
typedef __attribute__((ext_vector_type(4))) float f32x4;

__device__ __forceinline__ float lrelu(float v) { return v >= 0.f ? v : SLOPE * v; }

__device__ __forceinline__ ushort f2bf(float f) {
    uint u = __float_as_uint(f);
    return (ushort)((u + 0x7fffu + ((u >> 16) & 1u)) >> 16);
}

// fp32 W[128][128] row-major -> bf16 wl[g*WSTR + f] = W[f][g] (transposed), 512 thr
__device__ __forceinline__ void wtrans(const float* __restrict__ W, ushort* wl, int tid) {
#pragma unroll
    for (int u = 0; u < 4; u++) {
        const int g = tid & 127;
        const int fgrp = (tid >> 7) + u * 4;       // 0..15
        short8 v;
#pragma unroll
        for (int j = 0; j < 8; j++) v[j] = (short)f2bf(W[(fgrp * 8 + j) * 128 + g]);
        *(short8*)&wl[g * WSTR + fgrp * 8] = v;
    }
}

// ---------------------------------------------------------------------------
// K1: w1 = lrelu(x@W3+b3) [bf16 row-major], w2t[b][f][j] = lrelu(x@W4+b4)^T,
//     xt[b][g][j] = x^T (bf16), diag[i] = dot(w1_i, w2_i).
// 64 rows / block, 512 threads, grid 256.  Weights transposed into LDS per block.
// ---------------------------------------------------------------------------
__global__ __launch_bounds__(512) void k_w12(
    const float* __restrict__ x,
    const float* __restrict__ W3, const float* __restrict__ b3,
    const float* __restrict__ W4, const float* __restrict__ b4,
    ushort* __restrict__ w1b, ushort* __restrict__ w2t,
    ushort* __restrict__ xt, float* __restrict__ diag)
{
    __shared__ __align__(16) char smem[87040];
    ushort* xs = (ushort*)smem;               // 17408: x tile
    ushort* wA = (ushort*)(smem + 17408);     // 34816: W3^T
    ushort* wB = (ushort*)(smem + 52224);     // 34816: W4^T
    __shared__ float diag_s[64];

    const int tid = threadIdx.x;            // 0..511
    const int row0 = blockIdx.x * 64;
    const int b = row0 >> 11;               // batch
    const int jloc0 = row0 & 2047;          // row within batch

    if (tid < 64) diag_s[tid] = 0.f;

    // stage x tile -> bf16 LDS (row-major, padded): 2048 float4, 4 per thread
    const float4* xg4 = (const float4*)(x + (size_t)row0 * FF);
#pragma unroll
    for (int i = 0; i < 4; i++) {
        const int f4 = i * 512 + tid;
        const int row = f4 >> 5;
        const int k = (f4 & 31) * 4;
        float4 v = xg4[f4];
        ushort4 h;
        h.x = f2bf(v.x); h.y = f2bf(v.y); h.z = f2bf(v.z); h.w = f2bf(v.w);
        *(ushort4*)&xs[row * TSTR + k] = h;
    }
    wtrans(W3, wA, tid);
    wtrans(W4, wB, tid);
    __syncthreads();

    // write xt[b][g][jloc0..+64] from LDS (transposed read), 16 j per thread
    {
        const int g = tid >> 2;
        const int h = tid & 3;
        uint p[8];
#pragma unroll
        for (int jj = 0; jj < 8; jj++) {
            const uint lo = xs[(h * 16 + jj * 2) * TSTR + g];
            const uint hi = xs[(h * 16 + jj * 2 + 1) * TSTR + g];
            p[jj] = lo | (hi << 16);
        }
        uint4* dst = (uint4*)&xt[(size_t)b * (FF * NN) + (size_t)g * NN + jloc0 + h * 16];
        dst[0] = make_uint4(p[0], p[1], p[2], p[3]);
        dst[1] = make_uint4(p[4], p[5], p[6], p[7]);
    }

    const int lane = tid & 63;
    const int wave = tid >> 6;     // 0..7 = column tile (16 cols each)
    const int c = lane & 15;
    const int quad = lane >> 4;
    const int gcol = wave * 16 + c;

    f32x4 acc1[4], acc2[4];
#pragma unroll
    for (int rt = 0; rt < 4; rt++) { acc1[rt] = (f32x4)0.f; acc2[rt] = (f32x4)0.f; }

#pragma unroll
    for (int kk = 0; kk < 4; kk++) {
        short8 bf3 = *(const short8*)&wA[gcol * WSTR + kk * 32 + quad * 8];
        short8 bf4 = *(const short8*)&wB[gcol * WSTR + kk * 32 + quad * 8];
#pragma unroll
        for (int rt = 0; rt < 4; rt++) {
            short8 a = *(const short8*)&xs[(rt * 16 + c) * TSTR + kk * 32 + quad * 8];
            acc1[rt] = __builtin_amdgcn_mfma_f32_16x16x32_bf16(a, bf3, acc1[rt], 0, 0, 0);
            acc2[rt] = __builtin_amdgcn_mfma_f32_16x16x32_bf16(a, bf4, acc2[rt], 0, 0, 0);
        }
    }

    const float bb3 = b3[gcol], bb4 = b4[gcol];
    float dpar[4][4];
#pragma unroll
    for (int rt = 0; rt < 4; rt++) {
        ushort w2p[4];
#pragma unroll
        for (int r = 0; r < 4; r++) {
            const float v1 = lrelu(acc1[rt][r] + bb3);
            const float v2 = lrelu(acc2[rt][r] + bb4);
            const int grow = row0 + rt * 16 + quad * 4 + r;
            w1b[(size_t)grow * FF + gcol] = f2bf(v1);
            w2p[r] = f2bf(v2);
            dpar[rt][r] = v1 * v2;
        }
        const uint lo = (uint)w2p[0] | ((uint)w2p[1] << 16);
        const uint hi = (uint)w2p[2] | ((uint)w2p[3] << 16);
        uint2* dst = (uint2*)&w2t[(size_t)b * (FF * NN) + (size_t)gcol * NN +
                                  jloc0 + rt * 16 + quad * 4];
        *dst = make_uint2(lo, hi);
    }

#pragma unroll
    for (int rt = 0; rt < 4; rt++) {
#pragma unroll
        for (int r = 0; r < 4; r++) {
            float dp = dpar[rt][r];
            dp += __shfl_xor(dp, 1, 64);
            dp += __shfl_xor(dp, 2, 64);
            dp += __shfl_xor(dp, 4, 64);
            dp += __shfl_xor(dp, 8, 64);
            if (c == 0) atomicAdd(&diag_s[rt * 16 + quad * 4 + r], dp);
        }
    }
    __syncthreads();
    if (tid < 64) diag[row0 + tid] = diag_s[tid];
}

// ---------------------------------------------------------------------------
// K2: St[b][g][f] = bf16( sum_j xt[b][g][j] * w2t[b][f][j] )
// 512 blocks x 256 thr (2 blocks/CU = 8 waves/CU for latency hiding).
// Block = (b XCD-aligned, gq 16g, fs 16f); 4 waves split K=2048 into 512 each.
// ---------------------------------------------------------------------------
__global__ __launch_bounds__(256) void k_S2(
    const ushort* __restrict__ xt, const ushort* __restrict__ w2t,
    ushort* __restrict__ St)
{
    __shared__ float red[4][256];   // 4 KB
    const int tid = threadIdx.x;
    const int lane = tid & 63;
    const int wave = tid >> 6;
    const int c = lane & 15;
    const int quad = lane >> 4;

    const int b     = blockIdx.x & 7;        // XCD-aligned batch
    const int slice = blockIdx.x >> 3;       // 0..63
    const int gq    = slice >> 3;            // g-group (16 g)
    const int fs    = slice & 7;             // f-strip (16 f)

    const ushort* xtb = xt + (size_t)b * (FF * NN);
    const ushort* w2b = w2t + (size_t)b * (FF * NN);

    const int j0 = wave * 512 + quad * 8;
    const ushort* a0p = &xtb[(gq * 16 + c) * NN + j0];
    const ushort* bp  = &w2b[(fs * 16 + c) * NN + j0];

    f32x4 acc0 = (f32x4)0.f;
#pragma unroll
    for (int it = 0; it < 16; it++) {
        short8 a0 = *(const short8*)(a0p + it * 32);
        short8 bf = *(const short8*)(bp + it * 32);
        acc0 = __builtin_amdgcn_mfma_f32_16x16x32_bf16(a0, bf, acc0, 0, 0, 0);
    }

#pragma unroll
    for (int r = 0; r < 4; r++)
        red[wave][(quad * 4 + r) * 16 + c] = acc0[r];
    __syncthreads();

    {
        const float s = red[0][tid] + red[1][tid] + red[2][tid] + red[3][tid];
        const int gl = tid >> 4;
        const int fl = tid & 15;
        St[(size_t)b * (FF * FF) + (size_t)(gq * 16 + gl) * FF + fs * 16 + fl] = f2bf(s);
    }
}

// ---------------------------------------------------------------------------
// K3: fused k_out(layer l) + k_w12(layer l+1), 64-row tiles, 512 thr, grid 256.
// ALL weight transposes (W5, W3', W4') hoisted to kernel start into separate
// LDS buffers (139.5 KB total) so phase B has no serial transpose.
// ---------------------------------------------------------------------------
__global__ __launch_bounds__(512) void k_out_w12(
    const float* __restrict__ x, const ushort* __restrict__ w1b_in,
    const ushort* __restrict__ St, const float* __restrict__ diag_in,
    const float* __restrict__ W5, const float* __restrict__ b5,
    float* __restrict__ out,
    const float* __restrict__ W3n, const float* __restrict__ b3n,
    const float* __restrict__ W4n, const float* __restrict__ b4n,
    ushort* __restrict__ w1b, ushort* __restrict__ w2t,
    ushort* __restrict__ xt, float* __restrict__ diag)
{
    __shared__ __align__(16) char smem[139264];
    ushort* sA = (ushort*)smem;               // 17408: w1 tile -> out tile
    ushort* sB = (ushort*)(smem + 17408);     // 17408: msg tile
    ushort* wA = (ushort*)(smem + 34816);     // 34816: W5^T
    ushort* wB = (ushort*)(smem + 69632);     // 34816: W3'^T
    ushort* wC = (ushort*)(smem + 104448);    // 34816: W4'^T
    __shared__ float diag_s[64];

    const int tid = threadIdx.x;
    const int row0 = blockIdx.x * 64;
    const int b = row0 >> 11;
    const int jloc0 = row0 & 2047;
    const ushort* Sb = St + (size_t)b * (FF * FF);

    if (tid < 64) diag_s[tid] = 0.f;

    // ---- stage w1 tile + ALL weight transposes up front ----
#pragma unroll
    for (int i = 0; i < 2; i++) {
        const int off = (i * 512 + tid) * 8;
        const int row = off >> 7;
        const int k = off & 127;
        short8 v = *(const short8*)&w1b_in[(size_t)row0 * FF + off];
        *(short8*)&sA[row * TSTR + k] = v;
    }
    wtrans(W5, wA, tid);
    wtrans(W3n, wB, tid);
    wtrans(W4n, wC, tid);
    __syncthreads();

    const int lane = tid & 63;
    const int wave = tid >> 6;
    const int c = lane & 15;
    const int quad = lane >> 4;
    const int gcol = wave * 16 + c;

    // ---- Phase A: out = lrelu((w1@S - diag*x)/(N-1) @ W5 + b5) + x ----
    f32x4 accm[4];
#pragma unroll
    for (int rt = 0; rt < 4; rt++) accm[rt] = (f32x4)0.f;

#pragma unroll
    for (int kk = 0; kk < 4; kk++) {
        short8 bf = *(const short8*)&Sb[gcol * 128 + kk * 32 + quad * 8];
#pragma unroll
        for (int rt = 0; rt < 4; rt++) {
            short8 a = *(const short8*)&sA[(rt * 16 + c) * TSTR + kk * 32 + quad * 8];
            accm[rt] = __builtin_amdgcn_mfma_f32_16x16x32_bf16(a, bf, accm[rt], 0, 0, 0);
        }
    }

    const float inv = 1.f / (float)(NN - 1);
    float xsv[4][4];
#pragma unroll
    for (int rt = 0; rt < 4; rt++) {
        float dg[4];
#pragma unroll
        for (int r = 0; r < 4; r++) dg[r] = diag_in[row0 + rt * 16 + quad * 4 + r];
#pragma unroll
        for (int r = 0; r < 4; r++) {
            const int lrow = rt * 16 + quad * 4 + r;
            const float xv = x[(size_t)(row0 + lrow) * FF + gcol];
            xsv[rt][r] = xv;
            const float m = (accm[rt][r] - dg[r] * xv) * inv;
            sB[lrow * TSTR + gcol] = f2bf(m);
        }
    }
    __syncthreads();   // sB ready; all sA (w1) reads done

    f32x4 acc2[4];
#pragma unroll
    for (int rt = 0; rt < 4; rt++) acc2[rt] = (f32x4)0.f;

#pragma unroll
    for (int kk = 0; kk < 4; kk++) {
        short8 bf = *(const short8*)&wA[gcol * WSTR + kk * 32 + quad * 8];
#pragma unroll
        for (int rt = 0; rt < 4; rt++) {
            short8 a = *(const short8*)&sB[(rt * 16 + c) * TSTR + kk * 32 + quad * 8];
            acc2[rt] = __builtin_amdgcn_mfma_f32_16x16x32_bf16(a, bf, acc2[rt], 0, 0, 0);
        }
    }

    // epilogue: write out (fp32 global) + stash bf16 out tile in sA
    const float bb = b5[gcol];
#pragma unroll
    for (int rt = 0; rt < 4; rt++) {
#pragma unroll
        for (int r = 0; r < 4; r++) {
            const int lrow = rt * 16 + quad * 4 + r;
            const float ov = lrelu(acc2[rt][r] + bb) + xsv[rt][r];
            out[(size_t)(row0 + lrow) * FF + gcol] = ov;
            sA[lrow * TSTR + gcol] = f2bf(ov);
        }
    }
    __syncthreads();   // sA = out tile visible to all waves

    // ---- Phase B: next layer's w1/w2/xt/diag from sA (weights pre-staged) ----
    {
        const int g = tid >> 2;
        const int h = tid & 3;
        uint p[8];
#pragma unroll
        for (int jj = 0; jj < 8; jj++) {
            const uint lo = sA[(h * 16 + jj * 2) * TSTR + g];
            const uint hi = sA[(h * 16 + jj * 2 + 1) * TSTR + g];
            p[jj] = lo | (hi << 16);
        }
        uint4* dst = (uint4*)&xt[(size_t)b * (FF * NN) + (size_t)g * NN + jloc0 + h * 16];
        dst[0] = make_uint4(p[0], p[1], p[2], p[3]);
        dst[1] = make_uint4(p[4], p[5], p[6], p[7]);
    }

    f32x4 acc1n[4], acc2n[4];
#pragma unroll
    for (int rt = 0; rt < 4; rt++) { acc1n[rt] = (f32x4)0.f; acc2n[rt] = (f32x4)0.f; }

#pragma unroll
    for (int kk = 0; kk < 4; kk++) {
        short8 bf3 = *(const short8*)&wB[gcol * WSTR + kk * 32 + quad * 8];
        short8 bf4 = *(const short8*)&wC[gcol * WSTR + kk * 32 + quad * 8];
#pragma unroll
        for (int rt = 0; rt < 4; rt++) {
            short8 a = *(const short8*)&sA[(rt * 16 + c) * TSTR + kk * 32 + quad * 8];
            acc1n[rt] = __builtin_amdgcn_mfma_f32_16x16x32_bf16(a, bf3, acc1n[rt], 0, 0, 0);
            acc2n[rt] = __builtin_amdgcn_mfma_f32_16x16x32_bf16(a, bf4, acc2n[rt], 0, 0, 0);
        }
    }

    const float bb3 = b3n[gcol], bb4 = b4n[gcol];
    float dpar[4][4];
#pragma unroll
    for (int rt = 0; rt < 4; rt++) {
        ushort w2p[4];
#pragma unroll
        for (int r = 0; r < 4; r++) {
            const float v1 = lrelu(acc1n[rt][r] + bb3);
            const float v2 = lrelu(acc2n[rt][r] + bb4);
            const int grow = row0 + rt * 16 + quad * 4 + r;
            w1b[(size_t)grow * FF + gcol] = f2bf(v1);
            w2p[r] = f2bf(v2);
            dpar[rt][r] = v1 * v2;
        }
        const uint lo = (uint)w2p[0] | ((uint)w2p[1] << 16);
        const uint hi = (uint)w2p[2] | ((uint)w2p[3] << 16);
        uint2* dst = (uint2*)&w2t[(size_t)b * (FF * NN) + (size_t)gcol * NN +
                                  jloc0 + rt * 16 + quad * 4];
        *dst = make_uint2(lo, hi);
    }

#pragma unroll
    for (int rt = 0; rt < 4; rt++) {
#pragma unroll
        for (int r = 0; r < 4; r++) {
            float dp = dpar[rt][r];
            dp += __shfl_xor(dp, 1, 64);
            dp += __shfl_xor(dp, 2, 64);
            dp += __shfl_xor(dp, 4, 64);
            dp += __shfl_xor(dp, 8, 64);
            if (c == 0) atomicAdd(&diag_s[rt * 16 + quad * 4 + r], dp);
        }
    }
    __syncthreads();
    if (tid < 64) diag[row0 + tid] = diag_s[tid];
}

// ---------------------------------------------------------------------------
// K4: layer-1 out.  Residual base = out (layer-0 result).
// ---------------------------------------------------------------------------
__global__ __launch_bounds__(512) void k_out(
    const float* __restrict__ xres, const ushort* __restrict__ w1b,
    const ushort* __restrict__ St, const float* __restrict__ diag,
    const float* __restrict__ W5n, const float* __restrict__ b5n,
    float* __restrict__ out)
{
    __shared__ __align__(16) char smem[69632];
    ushort* w1s = (ushort*)smem;              // 17408
    ushort* ms  = (ushort*)(smem + 17408);    // 17408
    ushort* wA  = (ushort*)(smem + 34816);    // 34816: W5'^T

    const int tid = threadIdx.x;
    const int row0 = blockIdx.x * 64;
    const int b = row0 >> 11;
    const ushort* Sb = St + (size_t)b * (FF * FF);

#pragma unroll
    for (int i = 0; i < 2; i++) {
        const int off = (i * 512 + tid) * 8;
        const int row = off >> 7;
        const int k = off & 127;
        short8 v = *(const short8*)&w1b[(size_t)row0 * FF + off];
        *(short8*)&w1s[row * TSTR + k] = v;
    }
    wtrans(W5n, wA, tid);
    __syncthreads();

    const int lane = tid & 63;
    const int wave = tid >> 6;
    const int c = lane & 15;
    const int quad = lane >> 4;
    const int gcol = wave * 16 + c;

    f32x4 accm[4];
#pragma unroll
    for (int rt = 0; rt < 4; rt++) accm[rt] = (f32x4)0.f;

#pragma unroll
    for (int kk = 0; kk < 4; kk++) {
        short8 bf = *(const short8*)&Sb[gcol * 128 + kk * 32 + quad * 8];
#pragma unroll
        for (int rt = 0; rt < 4; rt++) {
            short8 a = *(const short8*)&w1s[(rt * 16 + c) * TSTR + kk * 32 + quad * 8];
            accm[rt] = __builtin_amdgcn_mfma_f32_16x16x32_bf16(a, bf, accm[rt], 0, 0, 0);
        }
    }

    const float inv = 1.f / (float)(NN - 1);
    float xsv[4][4];
#pragma unroll
    for (int rt = 0; rt < 4; rt++) {
        float dg[4];
#pragma unroll
        for (int r = 0; r < 4; r++) dg[r] = diag[row0 + rt * 16 + quad * 4 + r];
#pragma unroll
        for (int r = 0; r < 4; r++) {
            const int lrow = rt * 16 + quad * 4 + r;
            const float xv = xres[(size_t)(row0 + lrow) * FF + gcol];
            xsv[rt][r] = xv;
            const float m = (accm[rt][r] - dg[r] * xv) * inv;
            ms[lrow * TSTR + gcol] = f2bf(m);
        }
    }
    __syncthreads();

    f32x4 acc2[4];
#pragma unroll
    for (int rt = 0; rt < 4; rt++) acc2[rt] = (f32x4)0.f;

#pragma unroll
    for (int kk = 0; kk < 4; kk++) {
        short8 bf = *(const short8*)&wA[gcol * WSTR + kk * 32 + quad * 8];
#pragma unroll
        for (int rt = 0; rt < 4; rt++) {
            short8 a = *(const short8*)&ms[(rt * 16 + c) * TSTR + kk * 32 + quad * 8];
            acc2[rt] = __builtin_amdgcn_mfma_f32_16x16x32_bf16(a, bf, acc2[rt], 0, 0, 0);
        }
    }

    const float bb = b5n[gcol];
#pragma unroll
    for (int rt = 0; rt < 4; rt++) {
#pragma unroll
        for (int r = 0; r < 4; r++) {
            const int grow = row0 + rt * 16 + quad * 4 + r;
            out[(size_t)grow * FF + gcol] = lrelu(acc2[rt][r] + bb) + xsv[rt][r];
        }
    }
}

// ---------------------------------------------------------------------------
extern "C" void kernel_launch(void* const* d_in, const int* in_sizes, int n_in,
                              void* d_out, int out_size, void* d_ws, size_t ws_size,
                              hipStream_t stream)
{
    const float* x  = (const float*)d_in[0];
    const float* W3 = (const float*)d_in[1];
    const float* b3 = (const float*)d_in[2];
    const float* W4 = (const float*)d_in[3];
    const float* b4 = (const float*)d_in[4];
    const float* W5 = (const float*)d_in[5];
    const float* b5 = (const float*)d_in[6];
    float* out = (float*)d_out;

    char* ws = (char*)d_ws;
    ushort* w1b  = (ushort*)(ws);                          // 4 MB bf16 [16384][128]
    ushort* w2t  = (ushort*)(ws + ((size_t)4  << 20));     // 4 MB bf16 [8][128][2048]
    ushort* xt   = (ushort*)(ws + ((size_t)8  << 20));     // 4 MB bf16 [8][128][2048]
    float*  diag = (float*) (ws + ((size_t)12 << 20));     // 64 KB fp32 [16384]
    ushort* St   = (ushort*)(ws + ((size_t)13 << 20));     // 256 KB bf16 [8][128][128]

    // Layer 0
    k_w12<<<256, 512, 0, stream>>>(x, W3, b3, W4, b4, w1b, w2t, xt, diag);
    k_S2<<<512, 256, 0, stream>>>(xt, w2t, St);
    // Layer 0 output + Layer 1 w12, fused
    k_out_w12<<<256, 512, 0, stream>>>(x, w1b, St, diag, W5, b5, out,
                                       W3 + 16384, b3 + FF, W4 + 16384, b4 + FF,
                                       w1b, w2t, xt, diag);
    // Layer 1
    k_S2<<<512, 256, 0, stream>>>(xt, w2t, St);
    k_out<<<256, 512, 0, stream>>>(out, w1b, St, diag, W5 + 16384, b5 + FF, out);
}

// Round 10
// 117.011 us; speedup vs baseline: 1.0439x; 1.0439x over previous
//
#include <hip/hip_runtime.h>

#define NN 2048
#define FF 128
#define SLOPE 0.1f
#define WSTR 136    // bf16 LDS stride for transposed 128x128 weights
#define TSTR 136    // bf16 LDS stride for 64-row tiles

typedef __attribute__((ext_vector_type(8))) short short8;
typedef __attribute__((ext_vector_type(4))) float f32x4;

__device__ __forceinline__ float lrelu(float v) { return v >= 0.f ? v : SLOPE * v; }

__device__ __forceinline__ ushort f2bf(float f) {
    uint u = __float_as_uint(f);
    return (ushort)((u + 0x7fffu + ((u >> 16) & 1u)) >> 16);
}

// fp32 W[128][128] row-major -> bf16 wl[g*WSTR + f] = W[f][g] (transposed), 512 thr
__device__ __forceinline__ void wtrans(const float* __restrict__ W, ushort* wl, int tid) {
#pragma unroll
    for (int u = 0; u < 4; u++) {
        const int g = tid & 127;
        const int fgrp = (tid >> 7) + u * 4;       // 0..15
        short8 v;
#pragma unroll
        for (int j = 0; j < 8; j++) v[j] = (short)f2bf(W[(fgrp * 8 + j) * 128 + g]);
        *(short8*)&wl[g * WSTR + fgrp * 8] = v;
    }
}

// ---------------------------------------------------------------------------
// K1: w1 = lrelu(x@W3+b3) [bf16 row-major], w2t[b][f][j] = lrelu(x@W4+b4)^T,
//     xt[b][g][j] = x^T (bf16), diag[i] = dot(w1_i, w2_i).
// 64 rows / block, 512 threads, grid 256.  Weights transposed into LDS per block.
// ---------------------------------------------------------------------------
__global__ __launch_bounds__(512) void k_w12(
    const float* __restrict__ x,
    const float* __restrict__ W3, const float* __restrict__ b3,
    const float* __restrict__ W4, const float* __restrict__ b4,
    ushort* __restrict__ w1b, ushort* __restrict__ w2t,
    ushort* __restrict__ xt, float* __restrict__ diag)
{
    __shared__ __align__(16) char smem[87040];
    ushort* xs = (ushort*)smem;               // 17408: x tile
    ushort* wA = (ushort*)(smem + 17408);     // 34816: W3^T
    ushort* wB = (ushort*)(smem + 52224);     // 34816: W4^T
    __shared__ float diag_s[64];

    const int tid = threadIdx.x;            // 0..511
    const int row0 = blockIdx.x * 64;
    const int b = row0 >> 11;               // batch
    const int jloc0 = row0 & 2047;          // row within batch

    if (tid < 64) diag_s[tid] = 0.f;

    // stage x tile -> bf16 LDS (row-major, padded): 2048 float4, 4 per thread
    const float4* xg4 = (const float4*)(x + (size_t)row0 * FF);
#pragma unroll
    for (int i = 0; i < 4; i++) {
        const int f4 = i * 512 + tid;
        const int row = f4 >> 5;
        const int k = (f4 & 31) * 4;
        float4 v = xg4[f4];
        ushort4 h;
        h.x = f2bf(v.x); h.y = f2bf(v.y); h.z = f2bf(v.z); h.w = f2bf(v.w);
        *(ushort4*)&xs[row * TSTR + k] = h;
    }
    wtrans(W3, wA, tid);
    wtrans(W4, wB, tid);
    __syncthreads();

    // write xt[b][g][jloc0..+64] from LDS (transposed read), 16 j per thread
    {
        const int g = tid >> 2;
        const int h = tid & 3;
        uint p[8];
#pragma unroll
        for (int jj = 0; jj < 8; jj++) {
            const uint lo = xs[(h * 16 + jj * 2) * TSTR + g];
            const uint hi = xs[(h * 16 + jj * 2 + 1) * TSTR + g];
            p[jj] = lo | (hi << 16);
        }
        uint4* dst = (uint4*)&xt[(size_t)b * (FF * NN) + (size_t)g * NN + jloc0 + h * 16];
        dst[0] = make_uint4(p[0], p[1], p[2], p[3]);
        dst[1] = make_uint4(p[4], p[5], p[6], p[7]);
    }

    const int lane = tid & 63;
    const int wave = tid >> 6;     // 0..7 = column tile (16 cols each)
    const int c = lane & 15;
    const int quad = lane >> 4;
    const int gcol = wave * 16 + c;

    f32x4 acc1[4], acc2[4];
#pragma unroll
    for (int rt = 0; rt < 4; rt++) { acc1[rt] = (f32x4)0.f; acc2[rt] = (f32x4)0.f; }

#pragma unroll
    for (int kk = 0; kk < 4; kk++) {
        short8 bf3 = *(const short8*)&wA[gcol * WSTR + kk * 32 + quad * 8];
        short8 bf4 = *(const short8*)&wB[gcol * WSTR + kk * 32 + quad * 8];
#pragma unroll
        for (int rt = 0; rt < 4; rt++) {
            short8 a = *(const short8*)&xs[(rt * 16 + c) * TSTR + kk * 32 + quad * 8];
            acc1[rt] = __builtin_amdgcn_mfma_f32_16x16x32_bf16(a, bf3, acc1[rt], 0, 0, 0);
            acc2[rt] = __builtin_amdgcn_mfma_f32_16x16x32_bf16(a, bf4, acc2[rt], 0, 0, 0);
        }
    }

    const float bb3 = b3[gcol], bb4 = b4[gcol];
    float dpar[4][4];
#pragma unroll
    for (int rt = 0; rt < 4; rt++) {
        ushort w2p[4];
#pragma unroll
        for (int r = 0; r < 4; r++) {
            const float v1 = lrelu(acc1[rt][r] + bb3);
            const float v2 = lrelu(acc2[rt][r] + bb4);
            const int grow = row0 + rt * 16 + quad * 4 + r;
            w1b[(size_t)grow * FF + gcol] = f2bf(v1);
            w2p[r] = f2bf(v2);
            dpar[rt][r] = v1 * v2;
        }
        const uint lo = (uint)w2p[0] | ((uint)w2p[1] << 16);
        const uint hi = (uint)w2p[2] | ((uint)w2p[3] << 16);
        uint2* dst = (uint2*)&w2t[(size_t)b * (FF * NN) + (size_t)gcol * NN +
                                  jloc0 + rt * 16 + quad * 4];
        *dst = make_uint2(lo, hi);
    }

#pragma unroll
    for (int rt = 0; rt < 4; rt++) {
#pragma unroll
        for (int r = 0; r < 4; r++) {
            float dp = dpar[rt][r];
            dp += __shfl_xor(dp, 1, 64);
            dp += __shfl_xor(dp, 2, 64);
            dp += __shfl_xor(dp, 4, 64);
            dp += __shfl_xor(dp, 8, 64);
            if (c == 0) atomicAdd(&diag_s[rt * 16 + quad * 4 + r], dp);
        }
    }
    __syncthreads();
    if (tid < 64) diag[row0 + tid] = diag_s[tid];
}

// ---------------------------------------------------------------------------
// K2: St[b][g][f] = bf16( sum_j xt[b][g][j] * w2t[b][f][j] )
// 256 blocks x 256 thr (round-8 proven shape).  XCD-aware: b = bid & 7.
// ---------------------------------------------------------------------------
__global__ __launch_bounds__(256) void k_S2(
    const ushort* __restrict__ xt, const ushort* __restrict__ w2t,
    ushort* __restrict__ St)
{
    __shared__ float red[4][512];   // 8 KB
    const int tid = threadIdx.x;
    const int lane = tid & 63;
    const int wave = tid >> 6;
    const int c = lane & 15;
    const int quad = lane >> 4;

    const int b     = blockIdx.x & 7;        // XCD-aligned batch
    const int slice = blockIdx.x >> 3;       // 0..31
    const int gq    = slice >> 3;            // g-quarter (32 g)
    const int fs    = slice & 7;             // f-strip (16 f)

    const ushort* xtb = xt + (size_t)b * (FF * NN);
    const ushort* w2b = w2t + (size_t)b * (FF * NN);

    const int j0 = wave * 512 + quad * 8;
    const ushort* a0p = &xtb[(gq * 32 + c) * NN + j0];
    const ushort* a1p = &xtb[(gq * 32 + 16 + c) * NN + j0];
    const ushort* bp  = &w2b[(fs * 16 + c) * NN + j0];

    f32x4 acc0 = (f32x4)0.f, acc1 = (f32x4)0.f;
#pragma unroll
    for (int it = 0; it < 16; it++) {
        short8 a0 = *(const short8*)(a0p + it * 32);
        short8 a1 = *(const short8*)(a1p + it * 32);
        short8 bf = *(const short8*)(bp + it * 32);
        acc0 = __builtin_amdgcn_mfma_f32_16x16x32_bf16(a0, bf, acc0, 0, 0, 0);
        acc1 = __builtin_amdgcn_mfma_f32_16x16x32_bf16(a1, bf, acc1, 0, 0, 0);
    }

#pragma unroll
    for (int r = 0; r < 4; r++) {
        red[wave][(quad * 4 + r) * 16 + c] = acc0[r];
        red[wave][(16 + quad * 4 + r) * 16 + c] = acc1[r];
    }
    __syncthreads();

#pragma unroll
    for (int i = 0; i < 2; i++) {
        const int idx = i * 256 + tid;
        const float s = red[0][idx] + red[1][idx] + red[2][idx] + red[3][idx];
        const int gl = idx >> 4;
        const int fl = idx & 15;
        St[(size_t)b * (FF * FF) + (size_t)(gq * 32 + gl) * FF + fs * 16 + fl] = f2bf(s);
    }
}

// ---------------------------------------------------------------------------
// K3: fused k_out(layer l) + k_w12(layer l+1), 64-row tiles, 512 thr, grid 256.
// ALL weight transposes (W5, W3', W4') hoisted to kernel start into separate
// LDS buffers (139.5 KB) so phase B has no serial transpose (single change
// under test vs round-8).
// ---------------------------------------------------------------------------
__global__ __launch_bounds__(512) void k_out_w12(
    const float* __restrict__ x, const ushort* __restrict__ w1b_in,
    const ushort* __restrict__ St, const float* __restrict__ diag_in,
    const float* __restrict__ W5, const float* __restrict__ b5,
    float* __restrict__ out,
    const float* __restrict__ W3n, const float* __restrict__ b3n,
    const float* __restrict__ W4n, const float* __restrict__ b4n,
    ushort* __restrict__ w1b, ushort* __restrict__ w2t,
    ushort* __restrict__ xt, float* __restrict__ diag)
{
    __shared__ __align__(16) char smem[139264];
    ushort* sA = (ushort*)smem;               // 17408: w1 tile -> out tile
    ushort* sB = (ushort*)(smem + 17408);     // 17408: msg tile
    ushort* wA = (ushort*)(smem + 34816);     // 34816: W5^T
    ushort* wB = (ushort*)(smem + 69632);     // 34816: W3'^T
    ushort* wC = (ushort*)(smem + 104448);    // 34816: W4'^T
    __shared__ float diag_s[64];

    const int tid = threadIdx.x;
    const int row0 = blockIdx.x * 64;
    const int b = row0 >> 11;
    const int jloc0 = row0 & 2047;
    const ushort* Sb = St + (size_t)b * (FF * FF);

    if (tid < 64) diag_s[tid] = 0.f;

    // ---- stage w1 tile + ALL weight transposes up front ----
#pragma unroll
    for (int i = 0; i < 2; i++) {
        const int off = (i * 512 + tid) * 8;
        const int row = off >> 7;
        const int k = off & 127;
        short8 v = *(const short8*)&w1b_in[(size_t)row0 * FF + off];
        *(short8*)&sA[row * TSTR + k] = v;
    }
    wtrans(W5, wA, tid);
    wtrans(W3n, wB, tid);
    wtrans(W4n, wC, tid);
    __syncthreads();

    const int lane = tid & 63;
    const int wave = tid >> 6;
    const int c = lane & 15;
    const int quad = lane >> 4;
    const int gcol = wave * 16 + c;

    // ---- Phase A: out = lrelu((w1@S - diag*x)/(N-1) @ W5 + b5) + x ----
    f32x4 accm[4];
#pragma unroll
    for (int rt = 0; rt < 4; rt++) accm[rt] = (f32x4)0.f;

#pragma unroll
    for (int kk = 0; kk < 4; kk++) {
        short8 bf = *(const short8*)&Sb[gcol * 128 + kk * 32 + quad * 8];
#pragma unroll
        for (int rt = 0; rt < 4; rt++) {
            short8 a = *(const short8*)&sA[(rt * 16 + c) * TSTR + kk * 32 + quad * 8];
            accm[rt] = __builtin_amdgcn_mfma_f32_16x16x32_bf16(a, bf, accm[rt], 0, 0, 0);
        }
    }

    const float inv = 1.f / (float)(NN - 1);
    float xsv[4][4];
#pragma unroll
    for (int rt = 0; rt < 4; rt++) {
        float dg[4];
#pragma unroll
        for (int r = 0; r < 4; r++) dg[r] = diag_in[row0 + rt * 16 + quad * 4 + r];
#pragma unroll
        for (int r = 0; r < 4; r++) {
            const int lrow = rt * 16 + quad * 4 + r;
            const float xv = x[(size_t)(row0 + lrow) * FF + gcol];
            xsv[rt][r] = xv;
            const float m = (accm[rt][r] - dg[r] * xv) * inv;
            sB[lrow * TSTR + gcol] = f2bf(m);
        }
    }
    __syncthreads();   // sB ready; all sA (w1) reads done

    f32x4 acc2[4];
#pragma unroll
    for (int rt = 0; rt < 4; rt++) acc2[rt] = (f32x4)0.f;

#pragma unroll
    for (int kk = 0; kk < 4; kk++) {
        short8 bf = *(const short8*)&wA[gcol * WSTR + kk * 32 + quad * 8];
#pragma unroll
        for (int rt = 0; rt < 4; rt++) {
            short8 a = *(const short8*)&sB[(rt * 16 + c) * TSTR + kk * 32 + quad * 8];
            acc2[rt] = __builtin_amdgcn_mfma_f32_16x16x32_bf16(a, bf, acc2[rt], 0, 0, 0);
        }
    }

    // epilogue: write out (fp32 global) + stash bf16 out tile in sA
    const float bb = b5[gcol];
#pragma unroll
    for (int rt = 0; rt < 4; rt++) {
#pragma unroll
        for (int r = 0; r < 4; r++) {
            const int lrow = rt * 16 + quad * 4 + r;
            const float ov = lrelu(acc2[rt][r] + bb) + xsv[rt][r];
            out[(size_t)(row0 + lrow) * FF + gcol] = ov;
            sA[lrow * TSTR + gcol] = f2bf(ov);
        }
    }
    __syncthreads();   // sA = out tile visible to all waves

    // ---- Phase B: next layer's w1/w2/xt/diag from sA (weights pre-staged) ----
    {
        const int g = tid >> 2;
        const int h = tid & 3;
        uint p[8];
#pragma unroll
        for (int jj = 0; jj < 8; jj++) {
            const uint lo = sA[(h * 16 + jj * 2) * TSTR + g];
            const uint hi = sA[(h * 16 + jj * 2 + 1) * TSTR + g];
            p[jj] = lo | (hi << 16);
        }
        uint4* dst = (uint4*)&xt[(size_t)b * (FF * NN) + (size_t)g * NN + jloc0 + h * 16];
        dst[0] = make_uint4(p[0], p[1], p[2], p[3]);
        dst[1] = make_uint4(p[4], p[5], p[6], p[7]);
    }

    f32x4 acc1n[4], acc2n[4];
#pragma unroll
    for (int rt = 0; rt < 4; rt++) { acc1n[rt] = (f32x4)0.f; acc2n[rt] = (f32x4)0.f; }

#pragma unroll
    for (int kk = 0; kk < 4; kk++) {
        short8 bf3 = *(const short8*)&wB[gcol * WSTR + kk * 32 + quad * 8];
        short8 bf4 = *(const short8*)&wC[gcol * WSTR + kk * 32 + quad * 8];
#pragma unroll
        for (int rt = 0; rt < 4; rt++) {
            short8 a = *(const short8*)&sA[(rt * 16 + c) * TSTR + kk * 32 + quad * 8];
            acc1n[rt] = __builtin_amdgcn_mfma_f32_16x16x32_bf16(a, bf3, acc1n[rt], 0, 0, 0);
            acc2n[rt] = __builtin_amdgcn_mfma_f32_16x16x32_bf16(a, bf4, acc2n[rt], 0, 0, 0);
        }
    }

    const float bb3 = b3n[gcol], bb4 = b4n[gcol];
    float dpar[4][4];
#pragma unroll
    for (int rt = 0; rt < 4; rt++) {
        ushort w2p[4];
#pragma unroll
        for (int r = 0; r < 4; r++) {
            const float v1 = lrelu(acc1n[rt][r] + bb3);
            const float v2 = lrelu(acc2n[rt][r] + bb4);
            const int grow = row0 + rt * 16 + quad * 4 + r;
            w1b[(size_t)grow * FF + gcol] = f2bf(v1);
            w2p[r] = f2bf(v2);
            dpar[rt][r] = v1 * v2;
        }
        const uint lo = (uint)w2p[0] | ((uint)w2p[1] << 16);
        const uint hi = (uint)w2p[2] | ((uint)w2p[3] << 16);
        uint2* dst = (uint2*)&w2t[(size_t)b * (FF * NN) + (size_t)gcol * NN +
                                  jloc0 + rt * 16 + quad * 4];
        *dst = make_uint2(lo, hi);
    }

#pragma unroll
    for (int rt = 0; rt < 4; rt++) {
#pragma unroll
        for (int r = 0; r < 4; r++) {
            float dp = dpar[rt][r];
            dp += __shfl_xor(dp, 1, 64);
            dp += __shfl_xor(dp, 2, 64);
            dp += __shfl_xor(dp, 4, 64);
            dp += __shfl_xor(dp, 8, 64);
            if (c == 0) atomicAdd(&diag_s[rt * 16 + quad * 4 + r], dp);
        }
    }
    __syncthreads();
    if (tid < 64) diag[row0 + tid] = diag_s[tid];
}

// ---------------------------------------------------------------------------
// K4: layer-1 out.  Residual base = out (layer-0 result).
// ---------------------------------------------------------------------------
__global__ __launch_bounds__(512) void k_out(
    const float* __restrict__ xres, const ushort* __restrict__ w1b,
    const ushort* __restrict__ St, const float* __restrict__ diag,
    const float* __restrict__ W5n, const float* __restrict__ b5n,
    float* __restrict__ out)
{
    __shared__ __align__(16) char smem[69632];
    ushort* w1s = (ushort*)smem;              // 17408
    ushort* ms  = (ushort*)(smem + 17408);    // 17408
    ushort* wA  = (ushort*)(smem + 34816);    // 34816: W5'^T

    const int tid = threadIdx.x;
    const int row0 = blockIdx.x * 64;
    const int b = row0 >> 11;
    const ushort* Sb = St + (size_t)b * (FF * FF);

#pragma unroll
    for (int i = 0; i < 2; i++) {
        const int off = (i * 512 + tid) * 8;
        const int row = off >> 7;
        const int k = off & 127;
        short8 v = *(const short8*)&w1b[(size_t)row0 * FF + off];
        *(short8*)&w1s[row * TSTR + k] = v;
    }
    wtrans(W5n, wA, tid);
    __syncthreads();

    const int lane = tid & 63;
    const int wave = tid >> 6;
    const int c = lane & 15;
    const int quad = lane >> 4;
    const int gcol = wave * 16 + c;

    f32x4 accm[4];
#pragma unroll
    for (int rt = 0; rt < 4; rt++) accm[rt] = (f32x4)0.f;

#pragma unroll
    for (int kk = 0; kk < 4; kk++) {
        short8 bf = *(const short8*)&Sb[gcol * 128 + kk * 32 + quad * 8];
#pragma unroll
        for (int rt = 0; rt < 4; rt++) {
            short8 a = *(const short8*)&w1s[(rt * 16 + c) * TSTR + kk * 32 + quad * 8];
            accm[rt] = __builtin_amdgcn_mfma_f32_16x16x32_bf16(a, bf, accm[rt], 0, 0, 0);
        }
    }

    const float inv = 1.f / (float)(NN - 1);
    float xsv[4][4];
#pragma unroll
    for (int rt = 0; rt < 4; rt++) {
        float dg[4];
#pragma unroll
        for (int r = 0; r < 4; r++) dg[r] = diag[row0 + rt * 16 + quad * 4 + r];
#pragma unroll
        for (int r = 0; r < 4; r++) {
            const int lrow = rt * 16 + quad * 4 + r;
            const float xv = xres[(size_t)(row0 + lrow) * FF + gcol];
            xsv[rt][r] = xv;
            const float m = (accm[rt][r] - dg[r] * xv) * inv;
            ms[lrow * TSTR + gcol] = f2bf(m);
        }
    }
    __syncthreads();

    f32x4 acc2[4];
#pragma unroll
    for (int rt = 0; rt < 4; rt++) acc2[rt] = (f32x4)0.f;

#pragma unroll
    for (int kk = 0; kk < 4; kk++) {
        short8 bf = *(const short8*)&wA[gcol * WSTR + kk * 32 + quad * 8];
#pragma unroll
        for (int rt = 0; rt < 4; rt++) {
            short8 a = *(const short8*)&ms[(rt * 16 + c) * TSTR + kk * 32 + quad * 8];
            acc2[rt] = __builtin_amdgcn_mfma_f32_16x16x32_bf16(a, bf, acc2[rt], 0, 0, 0);
        }
    }

    const float bb = b5n[gcol];
#pragma unroll
    for (int rt = 0; rt < 4; rt++) {
#pragma unroll
        for (int r = 0; r < 4; r++) {
            const int grow = row0 + rt * 16 + quad * 4 + r;
            out[(size_t)grow * FF + gcol] = lrelu(acc2[rt][r] + bb) + xsv[rt][r];
        }
    }
}

// ---------------------------------------------------------------------------
extern "C" void kernel_launch(void* const* d_in, const int* in_sizes, int n_in,
                              void* d_out, int out_size, void* d_ws, size_t ws_size,
                              hipStream_t stream)
{
    const float* x  = (const float*)d_in[0];
    const float* W3 = (const float*)d_in[1];
    const float* b3 = (const float*)d_in[2];
    const float* W4 = (const float*)d_in[3];
    const float* b4 = (const float*)d_in[4];
    const float* W5 = (const float*)d_in[5];
    const float* b5 = (const float*)d_in[6];
    float* out = (float*)d_out;

    char* ws = (char*)d_ws;
    ushort* w1b  = (ushort*)(ws);                          // 4 MB bf16 [16384][128]
    ushort* w2t  = (ushort*)(ws + ((size_t)4  << 20));     // 4 MB bf16 [8][128][2048]
    ushort* xt   = (ushort*)(ws + ((size_t)8  << 20));     // 4 MB bf16 [8][128][2048]
    float*  diag = (float*) (ws + ((size_t)12 << 20));     // 64 KB fp32 [16384]
    ushort* St   = (ushort*)(ws + ((size_t)13 << 20));     // 256 KB bf16 [8][128][128]

    // Layer 0
    k_w12<<<256, 512, 0, stream>>>(x, W3, b3, W4, b4, w1b, w2t, xt, diag);
    k_S2<<<256, 256, 0, stream>>>(xt, w2t, St);
    // Layer 0 output + Layer 1 w12, fused
    k_out_w12<<<256, 512, 0, stream>>>(x, w1b, St, diag, W5, b5, out,
                                       W3 + 16384, b3 + FF, W4 + 16384, b4 + FF,
                                       w1b, w2t, xt, diag);
    // Layer 1
    k_S2<<<256, 256, 0, stream>>>(xt, w2t, St);
    k_out<<<256, 512, 0, stream>>>(out, w1b, St, diag, W5 + 16384, b5 + FF, out);
}

// Round 11
// 116.907 us; speedup vs baseline: 1.0448x; 1.0009x over previous
//
#include <hip/hip_runtime.h>

#define NN 2048
#define FF 128
#define SLOPE 0.1f
#define WSTR 136    // bf16 LDS stride for transposed 128x128 weights
#define TSTR 136    // bf16 LDS stride for 64-row tiles

typedef __attribute__((ext_vector_type(8))) short short8;
typedef __attribute__((ext_vector_type(4))) float f32x4;

__device__ __forceinline__ float lrelu(float v) { return v >= 0.f ? v : SLOPE * v; }

__device__ __forceinline__ ushort f2bf(float f) {
    uint u = __float_as_uint(f);
    return (ushort)((u + 0x7fffu + ((u >> 16) & 1u)) >> 16);
}

// fp32 W[128][128] row-major -> bf16 wl[g*WSTR + f] = W[f][g] (transposed), 512 thr
__device__ __forceinline__ void wtrans(const float* __restrict__ W, ushort* wl, int tid) {
#pragma unroll
    for (int u = 0; u < 4; u++) {
        const int g = tid & 127;
        const int fgrp = (tid >> 7) + u * 4;       // 0..15
        short8 v;
#pragma unroll
        for (int j = 0; j < 8; j++) v[j] = (short)f2bf(W[(fgrp * 8 + j) * 128 + g]);
        *(short8*)&wl[g * WSTR + fgrp * 8] = v;
    }
}

// ---------------------------------------------------------------------------
// K1: w1 = lrelu(x@W3+b3) [bf16 row-major], w2t[b][f][j] = lrelu(x@W4+b4)^T,
//     xt[b][g][j] = x^T (bf16), diag[i] = dot(w1_i, w2_i).
// 64 rows / block, 512 threads, grid 256.  Weights transposed into LDS per block.
// ---------------------------------------------------------------------------
__global__ __launch_bounds__(512) void k_w12(
    const float* __restrict__ x,
    const float* __restrict__ W3, const float* __restrict__ b3,
    const float* __restrict__ W4, const float* __restrict__ b4,
    ushort* __restrict__ w1b, ushort* __restrict__ w2t,
    ushort* __restrict__ xt, float* __restrict__ diag)
{
    __shared__ __align__(16) char smem[87040];
    ushort* xs = (ushort*)smem;               // 17408: x tile
    ushort* wA = (ushort*)(smem + 17408);     // 34816: W3^T
    ushort* wB = (ushort*)(smem + 52224);     // 34816: W4^T
    __shared__ float diag_s[64];

    const int tid = threadIdx.x;            // 0..511
    const int row0 = blockIdx.x * 64;
    const int b = row0 >> 11;               // batch
    const int jloc0 = row0 & 2047;          // row within batch

    if (tid < 64) diag_s[tid] = 0.f;

    // stage x tile -> bf16 LDS (row-major, padded): 2048 float4, 4 per thread
    const float4* xg4 = (const float4*)(x + (size_t)row0 * FF);
#pragma unroll
    for (int i = 0; i < 4; i++) {
        const int f4 = i * 512 + tid;
        const int row = f4 >> 5;
        const int k = (f4 & 31) * 4;
        float4 v = xg4[f4];
        ushort4 h;
        h.x = f2bf(v.x); h.y = f2bf(v.y); h.z = f2bf(v.z); h.w = f2bf(v.w);
        *(ushort4*)&xs[row * TSTR + k] = h;
    }
    wtrans(W3, wA, tid);
    wtrans(W4, wB, tid);
    __syncthreads();

    // write xt[b][g][jloc0..+64] from LDS (transposed read), 16 j per thread
    {
        const int g = tid >> 2;
        const int h = tid & 3;
        uint p[8];
#pragma unroll
        for (int jj = 0; jj < 8; jj++) {
            const uint lo = xs[(h * 16 + jj * 2) * TSTR + g];
            const uint hi = xs[(h * 16 + jj * 2 + 1) * TSTR + g];
            p[jj] = lo | (hi << 16);
        }
        uint4* dst = (uint4*)&xt[(size_t)b * (FF * NN) + (size_t)g * NN + jloc0 + h * 16];
        dst[0] = make_uint4(p[0], p[1], p[2], p[3]);
        dst[1] = make_uint4(p[4], p[5], p[6], p[7]);
    }

    const int lane = tid & 63;
    const int wave = tid >> 6;     // 0..7 = column tile (16 cols each)
    const int c = lane & 15;
    const int quad = lane >> 4;
    const int gcol = wave * 16 + c;

    f32x4 acc1[4], acc2[4];
#pragma unroll
    for (int rt = 0; rt < 4; rt++) { acc1[rt] = (f32x4)0.f; acc2[rt] = (f32x4)0.f; }

#pragma unroll
    for (int kk = 0; kk < 4; kk++) {
        short8 bf3 = *(const short8*)&wA[gcol * WSTR + kk * 32 + quad * 8];
        short8 bf4 = *(const short8*)&wB[gcol * WSTR + kk * 32 + quad * 8];
#pragma unroll
        for (int rt = 0; rt < 4; rt++) {
            short8 a = *(const short8*)&xs[(rt * 16 + c) * TSTR + kk * 32 + quad * 8];
            acc1[rt] = __builtin_amdgcn_mfma_f32_16x16x32_bf16(a, bf3, acc1[rt], 0, 0, 0);
            acc2[rt] = __builtin_amdgcn_mfma_f32_16x16x32_bf16(a, bf4, acc2[rt], 0, 0, 0);
        }
    }

    const float bb3 = b3[gcol], bb4 = b4[gcol];
    float dpar[4][4];
#pragma unroll
    for (int rt = 0; rt < 4; rt++) {
        ushort w2p[4];
#pragma unroll
        for (int r = 0; r < 4; r++) {
            const float v1 = lrelu(acc1[rt][r] + bb3);
            const float v2 = lrelu(acc2[rt][r] + bb4);
            const int grow = row0 + rt * 16 + quad * 4 + r;
            w1b[(size_t)grow * FF + gcol] = f2bf(v1);
            w2p[r] = f2bf(v2);
            dpar[rt][r] = v1 * v2;
        }
        const uint lo = (uint)w2p[0] | ((uint)w2p[1] << 16);
        const uint hi = (uint)w2p[2] | ((uint)w2p[3] << 16);
        uint2* dst = (uint2*)&w2t[(size_t)b * (FF * NN) + (size_t)gcol * NN +
                                  jloc0 + rt * 16 + quad * 4];
        *dst = make_uint2(lo, hi);
    }

#pragma unroll
    for (int rt = 0; rt < 4; rt++) {
#pragma unroll
        for (int r = 0; r < 4; r++) {
            float dp = dpar[rt][r];
            dp += __shfl_xor(dp, 1, 64);
            dp += __shfl_xor(dp, 2, 64);
            dp += __shfl_xor(dp, 4, 64);
            dp += __shfl_xor(dp, 8, 64);
            if (c == 0) atomicAdd(&diag_s[rt * 16 + quad * 4 + r], dp);
        }
    }
    __syncthreads();
    if (tid < 64) diag[row0 + tid] = diag_s[tid];
}

// ---------------------------------------------------------------------------
// K2: St[b][g][f] = bf16( sum_j xt[b][g][j] * w2t[b][f][j] )
// 256 blocks x 512 thr: SAME 32g x 16f tile & traffic as round-10, but 8-way
// K-split (j-slice 256/wave) -> 8 waves/CU (2/SIMD) for latency hiding.
// XCD-aware: b = bid & 7.
// ---------------------------------------------------------------------------
__global__ __launch_bounds__(512) void k_S2(
    const ushort* __restrict__ xt, const ushort* __restrict__ w2t,
    ushort* __restrict__ St)
{
    __shared__ float red[8][512];   // 16 KB
    const int tid = threadIdx.x;
    const int lane = tid & 63;
    const int wave = tid >> 6;      // 0..7
    const int c = lane & 15;
    const int quad = lane >> 4;

    const int b     = blockIdx.x & 7;        // XCD-aligned batch
    const int slice = blockIdx.x >> 3;       // 0..31
    const int gq    = slice >> 3;            // g-quarter (32 g)
    const int fs    = slice & 7;             // f-strip (16 f)

    const ushort* xtb = xt + (size_t)b * (FF * NN);
    const ushort* w2b = w2t + (size_t)b * (FF * NN);

    const int j0 = wave * 256 + quad * 8;
    const ushort* a0p = &xtb[(gq * 32 + c) * NN + j0];
    const ushort* a1p = &xtb[(gq * 32 + 16 + c) * NN + j0];
    const ushort* bp  = &w2b[(fs * 16 + c) * NN + j0];

    f32x4 acc0 = (f32x4)0.f, acc1 = (f32x4)0.f;
#pragma unroll
    for (int it = 0; it < 8; it++) {
        short8 a0 = *(const short8*)(a0p + it * 32);
        short8 a1 = *(const short8*)(a1p + it * 32);
        short8 bf = *(const short8*)(bp + it * 32);
        acc0 = __builtin_amdgcn_mfma_f32_16x16x32_bf16(a0, bf, acc0, 0, 0, 0);
        acc1 = __builtin_amdgcn_mfma_f32_16x16x32_bf16(a1, bf, acc1, 0, 0, 0);
    }

#pragma unroll
    for (int r = 0; r < 4; r++) {
        red[wave][(quad * 4 + r) * 16 + c] = acc0[r];
        red[wave][(16 + quad * 4 + r) * 16 + c] = acc1[r];
    }
    __syncthreads();

    {
        float s = 0.f;
#pragma unroll
        for (int w = 0; w < 8; w++) s += red[w][tid];
        const int gl = tid >> 4;
        const int fl = tid & 15;
        St[(size_t)b * (FF * FF) + (size_t)(gq * 32 + gl) * FF + fs * 16 + fl] = f2bf(s);
    }
}

// ---------------------------------------------------------------------------
// K3: fused k_out(layer l) + k_w12(layer l+1), 64-row tiles, 512 thr, grid 256.
// ALL weight transposes (W5, W3', W4') hoisted to kernel start into separate
// LDS buffers (139.5 KB) so phase B has no serial transpose.
// ---------------------------------------------------------------------------
__global__ __launch_bounds__(512) void k_out_w12(
    const float* __restrict__ x, const ushort* __restrict__ w1b_in,
    const ushort* __restrict__ St, const float* __restrict__ diag_in,
    const float* __restrict__ W5, const float* __restrict__ b5,
    float* __restrict__ out,
    const float* __restrict__ W3n, const float* __restrict__ b3n,
    const float* __restrict__ W4n, const float* __restrict__ b4n,
    ushort* __restrict__ w1b, ushort* __restrict__ w2t,
    ushort* __restrict__ xt, float* __restrict__ diag)
{
    __shared__ __align__(16) char smem[139264];
    ushort* sA = (ushort*)smem;               // 17408: w1 tile -> out tile
    ushort* sB = (ushort*)(smem + 17408);     // 17408: msg tile
    ushort* wA = (ushort*)(smem + 34816);     // 34816: W5^T
    ushort* wB = (ushort*)(smem + 69632);     // 34816: W3'^T
    ushort* wC = (ushort*)(smem + 104448);    // 34816: W4'^T
    __shared__ float diag_s[64];

    const int tid = threadIdx.x;
    const int row0 = blockIdx.x * 64;
    const int b = row0 >> 11;
    const int jloc0 = row0 & 2047;
    const ushort* Sb = St + (size_t)b * (FF * FF);

    if (tid < 64) diag_s[tid] = 0.f;

    // ---- stage w1 tile + ALL weight transposes up front ----
#pragma unroll
    for (int i = 0; i < 2; i++) {
        const int off = (i * 512 + tid) * 8;
        const int row = off >> 7;
        const int k = off & 127;
        short8 v = *(const short8*)&w1b_in[(size_t)row0 * FF + off];
        *(short8*)&sA[row * TSTR + k] = v;
    }
    wtrans(W5, wA, tid);
    wtrans(W3n, wB, tid);
    wtrans(W4n, wC, tid);
    __syncthreads();

    const int lane = tid & 63;
    const int wave = tid >> 6;
    const int c = lane & 15;
    const int quad = lane >> 4;
    const int gcol = wave * 16 + c;

    // ---- Phase A: out = lrelu((w1@S - diag*x)/(N-1) @ W5 + b5) + x ----
    f32x4 accm[4];
#pragma unroll
    for (int rt = 0; rt < 4; rt++) accm[rt] = (f32x4)0.f;

#pragma unroll
    for (int kk = 0; kk < 4; kk++) {
        short8 bf = *(const short8*)&Sb[gcol * 128 + kk * 32 + quad * 8];
#pragma unroll
        for (int rt = 0; rt < 4; rt++) {
            short8 a = *(const short8*)&sA[(rt * 16 + c) * TSTR + kk * 32 + quad * 8];
            accm[rt] = __builtin_amdgcn_mfma_f32_16x16x32_bf16(a, bf, accm[rt], 0, 0, 0);
        }
    }

    const float inv = 1.f / (float)(NN - 1);
    float xsv[4][4];
#pragma unroll
    for (int rt = 0; rt < 4; rt++) {
        float dg[4];
#pragma unroll
        for (int r = 0; r < 4; r++) dg[r] = diag_in[row0 + rt * 16 + quad * 4 + r];
#pragma unroll
        for (int r = 0; r < 4; r++) {
            const int lrow = rt * 16 + quad * 4 + r;
            const float xv = x[(size_t)(row0 + lrow) * FF + gcol];
            xsv[rt][r] = xv;
            const float m = (accm[rt][r] - dg[r] * xv) * inv;
            sB[lrow * TSTR + gcol] = f2bf(m);
        }
    }
    __syncthreads();   // sB ready; all sA (w1) reads done

    f32x4 acc2[4];
#pragma unroll
    for (int rt = 0; rt < 4; rt++) acc2[rt] = (f32x4)0.f;

#pragma unroll
    for (int kk = 0; kk < 4; kk++) {
        short8 bf = *(const short8*)&wA[gcol * WSTR + kk * 32 + quad * 8];
#pragma unroll
        for (int rt = 0; rt < 4; rt++) {
            short8 a = *(const short8*)&sB[(rt * 16 + c) * TSTR + kk * 32 + quad * 8];
            acc2[rt] = __builtin_amdgcn_mfma_f32_16x16x32_bf16(a, bf, acc2[rt], 0, 0, 0);
        }
    }

    // epilogue: write out (fp32 global) + stash bf16 out tile in sA
    const float bb = b5[gcol];
#pragma unroll
    for (int rt = 0; rt < 4; rt++) {
#pragma unroll
        for (int r = 0; r < 4; r++) {
            const int lrow = rt * 16 + quad * 4 + r;
            const float ov = lrelu(acc2[rt][r] + bb) + xsv[rt][r];
            out[(size_t)(row0 + lrow) * FF + gcol] = ov;
            sA[lrow * TSTR + gcol] = f2bf(ov);
        }
    }
    __syncthreads();   // sA = out tile visible to all waves

    // ---- Phase B: next layer's w1/w2/xt/diag from sA (weights pre-staged) ----
    {
        const int g = tid >> 2;
        const int h = tid & 3;
        uint p[8];
#pragma unroll
        for (int jj = 0; jj < 8; jj++) {
            const uint lo = sA[(h * 16 + jj * 2) * TSTR + g];
            const uint hi = sA[(h * 16 + jj * 2 + 1) * TSTR + g];
            p[jj] = lo | (hi << 16);
        }
        uint4* dst = (uint4*)&xt[(size_t)b * (FF * NN) + (size_t)g * NN + jloc0 + h * 16];
        dst[0] = make_uint4(p[0], p[1], p[2], p[3]);
        dst[1] = make_uint4(p[4], p[5], p[6], p[7]);
    }

    f32x4 acc1n[4], acc2n[4];
#pragma unroll
    for (int rt = 0; rt < 4; rt++) { acc1n[rt] = (f32x4)0.f; acc2n[rt] = (f32x4)0.f; }

#pragma unroll
    for (int kk = 0; kk < 4; kk++) {
        short8 bf3 = *(const short8*)&wB[gcol * WSTR + kk * 32 + quad * 8];
        short8 bf4 = *(const short8*)&wC[gcol * WSTR + kk * 32 + quad * 8];
#pragma unroll
        for (int rt = 0; rt < 4; rt++) {
            short8 a = *(const short8*)&sA[(rt * 16 + c) * TSTR + kk * 32 + quad * 8];
            acc1n[rt] = __builtin_amdgcn_mfma_f32_16x16x32_bf16(a, bf3, acc1n[rt], 0, 0, 0);
            acc2n[rt] = __builtin_amdgcn_mfma_f32_16x16x32_bf16(a, bf4, acc2n[rt], 0, 0, 0);
        }
    }

    const float bb3 = b3n[gcol], bb4 = b4n[gcol];
    float dpar[4][4];
#pragma unroll
    for (int rt = 0; rt < 4; rt++) {
        ushort w2p[4];
#pragma unroll
        for (int r = 0; r < 4; r++) {
            const float v1 = lrelu(acc1n[rt][r] + bb3);
            const float v2 = lrelu(acc2n[rt][r] + bb4);
            const int grow = row0 + rt * 16 + quad * 4 + r;
            w1b[(size_t)grow * FF + gcol] = f2bf(v1);
            w2p[r] = f2bf(v2);
            dpar[rt][r] = v1 * v2;
        }
        const uint lo = (uint)w2p[0] | ((uint)w2p[1] << 16);
        const uint hi = (uint)w2p[2] | ((uint)w2p[3] << 16);
        uint2* dst = (uint2*)&w2t[(size_t)b * (FF * NN) + (size_t)gcol * NN +
                                  jloc0 + rt * 16 + quad * 4];
        *dst = make_uint2(lo, hi);
    }

#pragma unroll
    for (int rt = 0; rt < 4; rt++) {
#pragma unroll
        for (int r = 0; r < 4; r++) {
            float dp = dpar[rt][r];
            dp += __shfl_xor(dp, 1, 64);
            dp += __shfl_xor(dp, 2, 64);
            dp += __shfl_xor(dp, 4, 64);
            dp += __shfl_xor(dp, 8, 64);
            if (c == 0) atomicAdd(&diag_s[rt * 16 + quad * 4 + r], dp);
        }
    }
    __syncthreads();
    if (tid < 64) diag[row0 + tid] = diag_s[tid];
}

// ---------------------------------------------------------------------------
// K4: layer-1 out.  Residual base = out (layer-0 result).
// ---------------------------------------------------------------------------
__global__ __launch_bounds__(512) void k_out(
    const float* __restrict__ xres, const ushort* __restrict__ w1b,
    const ushort* __restrict__ St, const float* __restrict__ diag,
    const float* __restrict__ W5n, const float* __restrict__ b5n,
    float* __restrict__ out)
{
    __shared__ __align__(16) char smem[69632];
    ushort* w1s = (ushort*)smem;              // 17408
    ushort* ms  = (ushort*)(smem + 17408);    // 17408
    ushort* wA  = (ushort*)(smem + 34816);    // 34816: W5'^T

    const int tid = threadIdx.x;
    const int row0 = blockIdx.x * 64;
    const int b = row0 >> 11;
    const ushort* Sb = St + (size_t)b * (FF * FF);

#pragma unroll
    for (int i = 0; i < 2; i++) {
        const int off = (i * 512 + tid) * 8;
        const int row = off >> 7;
        const int k = off & 127;
        short8 v = *(const short8*)&w1b[(size_t)row0 * FF + off];
        *(short8*)&w1s[row * TSTR + k] = v;
    }
    wtrans(W5n, wA, tid);
    __syncthreads();

    const int lane = tid & 63;
    const int wave = tid >> 6;
    const int c = lane & 15;
    const int quad = lane >> 4;
    const int gcol = wave * 16 + c;

    f32x4 accm[4];
#pragma unroll
    for (int rt = 0; rt < 4; rt++) accm[rt] = (f32x4)0.f;

#pragma unroll
    for (int kk = 0; kk < 4; kk++) {
        short8 bf = *(const short8*)&Sb[gcol * 128 + kk * 32 + quad * 8];
#pragma unroll
        for (int rt = 0; rt < 4; rt++) {
            short8 a = *(const short8*)&w1s[(rt * 16 + c) * TSTR + kk * 32 + quad * 8];
            accm[rt] = __builtin_amdgcn_mfma_f32_16x16x32_bf16(a, bf, accm[rt], 0, 0, 0);
        }
    }

    const float inv = 1.f / (float)(NN - 1);
    float xsv[4][4];
#pragma unroll
    for (int rt = 0; rt < 4; rt++) {
        float dg[4];
#pragma unroll
        for (int r = 0; r < 4; r++) dg[r] = diag[row0 + rt * 16 + quad * 4 + r];
#pragma unroll
        for (int r = 0; r < 4; r++) {
            const int lrow = rt * 16 + quad * 4 + r;
            const float xv = xres[(size_t)(row0 + lrow) * FF + gcol];
            xsv[rt][r] = xv;
            const float m = (accm[rt][r] - dg[r] * xv) * inv;
            ms[lrow * TSTR + gcol] = f2bf(m);
        }
    }
    __syncthreads();

    f32x4 acc2[4];
#pragma unroll
    for (int rt = 0; rt < 4; rt++) acc2[rt] = (f32x4)0.f;

#pragma unroll
    for (int kk = 0; kk < 4; kk++) {
        short8 bf = *(const short8*)&wA[gcol * WSTR + kk * 32 + quad * 8];
#pragma unroll
        for (int rt = 0; rt < 4; rt++) {
            short8 a = *(const short8*)&ms[(rt * 16 + c) * TSTR + kk * 32 + quad * 8];
            acc2[rt] = __builtin_amdgcn_mfma_f32_16x16x32_bf16(a, bf, acc2[rt], 0, 0, 0);
        }
    }

    const float bb = b5n[gcol];
#pragma unroll
    for (int rt = 0; rt < 4; rt++) {
#pragma unroll
        for (int r = 0; r < 4; r++) {
            const int grow = row0 + rt * 16 + quad * 4 + r;
            out[(size_t)grow * FF + gcol] = lrelu(acc2[rt][r] + bb) + xsv[rt][r];
        }
    }
}

// ---------------------------------------------------------------------------
extern "C" void kernel_launch(void* const* d_in, const int* in_sizes, int n_in,
                              void* d_out, int out_size, void* d_ws, size_t ws_size,
                              hipStream_t stream)
{
    const float* x  = (const float*)d_in[0];
    const float* W3 = (const float*)d_in[1];
    const float* b3 = (const float*)d_in[2];
    const float* W4 = (const float*)d_in[3];
    const float* b4 = (const float*)d_in[4];
    const float* W5 = (const float*)d_in[5];
    const float* b5 = (const float*)d_in[6];
    float* out = (float*)d_out;

    char* ws = (char*)d_ws;
    ushort* w1b  = (ushort*)(ws);                          // 4 MB bf16 [16384][128]
    ushort* w2t  = (ushort*)(ws + ((size_t)4  << 20));     // 4 MB bf16 [8][128][2048]
    ushort* xt   = (ushort*)(ws + ((size_t)8  << 20));     // 4 MB bf16 [8][128][2048]
    float*  diag = (float*) (ws + ((size_t)12 << 20));     // 64 KB fp32 [16384]
    ushort* St   = (ushort*)(ws + ((size_t)13 << 20));     // 256 KB bf16 [8][128][128]

    // Layer 0
    k_w12<<<256, 512, 0, stream>>>(x, W3, b3, W4, b4, w1b, w2t, xt, diag);
    k_S2<<<256, 512, 0, stream>>>(xt, w2t, St);
    // Layer 0 output + Layer 1 w12, fused
    k_out_w12<<<256, 512, 0, stream>>>(x, w1b, St, diag, W5, b5, out,
                                       W3 + 16384, b3 + FF, W4 + 16384, b4 + FF,
                                       w1b, w2t, xt, diag);
    // Layer 1
    k_S2<<<256, 512, 0, stream>>>(xt, w2t, St);
    k_out<<<256, 512, 0, stream>>>(out, w1b, St, diag, W5 + 16384, b5 + FF, out);
}